// Round 1
// baseline (1588.908 us; speedup 1.0000x reference)
//
#include <hip/hip_runtime.h>
#include <hip/hip_bf16.h>
#include <math.h>

#define BATCH 256
#define SEQ   512
#define INS   300
#define HID   128
#define NG    384   // 3*HID

// ---------- helpers ----------
__device__ __forceinline__ float bf2f(unsigned short u) {
    unsigned int v = ((unsigned int)u) << 16;
    return __uint_as_float(v);
}
__device__ __forceinline__ unsigned short f2bf(float f) {
    unsigned int u = __float_as_uint(f);
    unsigned int r = (u + 0x7FFFu + ((u >> 16) & 1u)) >> 16;
    return (unsigned short)r;
}

// ---------- Kernel A: xg[r, g] = sum_k x[row(r), k] * W_ih[g, k] + b_ih[g] ----------
// rows r = b*CT + (t - t0), 64x64 tile, K-chunks of 16, fp32 vector GEMM.
template <bool BF16>
__launch_bounds__(256)
__global__ void xg_gemm(const float* __restrict__ x,
                        const float* __restrict__ Wih,
                        const float* __restrict__ bih,
                        void* __restrict__ xg_out,
                        int t0, int CT)
{
    __shared__ alignas(16) float As[16][68];
    __shared__ alignas(16) float Bs[16][68];

    const int tid = threadIdx.x;
    const int tx = tid & 15;   // n quad
    const int ty = tid >> 4;   // m quad
    const int n0 = blockIdx.x * 64;   // gate dim (0..320)
    const int m0 = blockIdx.y * 64;   // row dim

    // staging map: each thread loads 4 consecutive k for one row
    const int sm = tid >> 2;          // 0..63
    const int sk = (tid & 3) * 4;     // 0,4,8,12

    const int r  = m0 + sm;
    const int b  = r / CT;
    const int t  = t0 + (r - b * CT);
    const float* xrow = x + (size_t)(b * SEQ + t) * INS;
    const float* wrow = Wih + (size_t)(n0 + sm) * INS;

    float acc[4][4] = {};

    for (int k0 = 0; k0 < INS; k0 += 16) {
        #pragma unroll
        for (int i = 0; i < 4; i++) {
            int k = k0 + sk + i;
            As[sk + i][sm] = (k < INS) ? xrow[k] : 0.f;
            Bs[sk + i][sm] = (k < INS) ? wrow[k] : 0.f;
        }
        __syncthreads();
        #pragma unroll
        for (int k = 0; k < 16; k++) {
            float4 a  = *(const float4*)&As[k][ty * 4];
            float4 bv = *(const float4*)&Bs[k][tx * 4];
            acc[0][0] += a.x * bv.x; acc[0][1] += a.x * bv.y; acc[0][2] += a.x * bv.z; acc[0][3] += a.x * bv.w;
            acc[1][0] += a.y * bv.x; acc[1][1] += a.y * bv.y; acc[1][2] += a.y * bv.z; acc[1][3] += a.y * bv.w;
            acc[2][0] += a.z * bv.x; acc[2][1] += a.z * bv.y; acc[2][2] += a.z * bv.z; acc[2][3] += a.z * bv.w;
            acc[3][0] += a.w * bv.x; acc[3][1] += a.w * bv.y; acc[3][2] += a.w * bv.z; acc[3][3] += a.w * bv.w;
        }
        __syncthreads();
    }

    const int n = n0 + tx * 4;
    float4 bias = *(const float4*)&bih[n];

    #pragma unroll
    for (int i = 0; i < 4; i++) {
        const size_t row = (size_t)(m0 + ty * 4 + i);
        float c0 = acc[i][0] + bias.x;
        float c1 = acc[i][1] + bias.y;
        float c2 = acc[i][2] + bias.z;
        float c3 = acc[i][3] + bias.w;
        if (BF16) {
            ushort4 v = make_ushort4(f2bf(c0), f2bf(c1), f2bf(c2), f2bf(c3));
            *(ushort4*)((unsigned short*)xg_out + row * NG + n) = v;
        } else {
            *(float4*)((float*)xg_out + row * NG + n) = make_float4(c0, c1, c2, c3);
        }
    }
}

// ---------- Kernel B: sequential GRU over a chunk of timesteps ----------
// 1 block per batch row; 384 threads; thread g owns W_hh row g in registers.
template <bool BF16>
__launch_bounds__(384)
__global__ void gru_chunk(const void* __restrict__ xg_in,
                          const float* __restrict__ Whh,
                          const float* __restrict__ bhh,
                          float* __restrict__ hstate,
                          int t0, int CT, int initial, int final_chunk,
                          const float* __restrict__ Wout,
                          const float* __restrict__ bout,
                          float* __restrict__ out)
{
    const int b = blockIdx.x;
    const int g = threadIdx.x;   // 0..383

    __shared__ alignas(16) float h_s[HID];
    __shared__ alignas(16) float hg_s[NG];
    __shared__ alignas(16) float red[2][HID];

    // load W_hh row g into registers (128 VGPRs, fully unrolled)
    float w[HID];
    const float* wr = Whh + (size_t)g * HID;
    #pragma unroll
    for (int k = 0; k < HID; k += 4) {
        float4 v = *(const float4*)&wr[k];
        w[k] = v.x; w[k + 1] = v.y; w[k + 2] = v.z; w[k + 3] = v.w;
    }
    const float bh = bhh[g];

    if (g < HID) h_s[g] = initial ? 0.f : hstate[b * HID + g];
    __syncthreads();

    const float* xgf = (const float*)xg_in;
    const unsigned short* xgb = (const unsigned short*)xg_in;

    for (int tt = 0; tt < CT; tt++) {
        const size_t base = ((size_t)b * CT + tt) * NG;
        // issue the xg loads for this step early so they're covered by the FMA phase
        float xr = 0.f, xz = 0.f, xn = 0.f;
        if (g < HID) {
            if (BF16) {
                xr = bf2f(xgb[base + g]);
                xz = bf2f(xgb[base + HID + g]);
                xn = bf2f(xgb[base + 2 * HID + g]);
            } else {
                xr = xgf[base + g];
                xz = xgf[base + HID + g];
                xn = xgf[base + 2 * HID + g];
            }
        }

        // hg[g] = b_hh[g] + h . W_hh[g,:]
        float a0 = 0.f, a1 = 0.f, a2 = 0.f, a3 = 0.f;
        #pragma unroll
        for (int k = 0; k < HID; k += 4) {
            float4 hv = *(const float4*)&h_s[k];
            a0 += hv.x * w[k];
            a1 += hv.y * w[k + 1];
            a2 += hv.z * w[k + 2];
            a3 += hv.w * w[k + 3];
        }
        hg_s[g] = bh + ((a0 + a1) + (a2 + a3));
        __syncthreads();

        if (g < HID) {
            float rg = 1.f / (1.f + __expf(-(xr + hg_s[g])));
            float zg = 1.f / (1.f + __expf(-(xz + hg_s[HID + g])));
            float nv = xn + rg * hg_s[2 * HID + g];
            float e  = __expf(2.f * nv);
            float ng = 1.f - 2.f / (e + 1.f);   // tanh, saturates correctly at +/-inf
            float hold = h_s[g];
            h_s[g] = (1.f - zg) * ng + zg * hold;
        }
        __syncthreads();
    }

    if (g < HID) hstate[b * HID + g] = h_s[g];

    if (final_chunk) {
        if (g < HID) {
            float f = h_s[g] > 0.f ? h_s[g] : 0.f;   // relu
            red[0][g] = f * Wout[g];
            red[1][g] = f * Wout[HID + g];
        }
        __syncthreads();
        if (g == 0) {
            float l0 = bout[0], l1 = bout[1];
            for (int k = 0; k < HID; k++) { l0 += red[0][k]; l1 += red[1][k]; }
            float m = fmaxf(l0, l1);
            float lse = m + logf(__expf(l0 - m) + __expf(l1 - m));
            out[b * 2 + 0] = l0 - lse;
            out[b * 2 + 1] = l1 - lse;
        }
    }
}

// ---------- launch ----------
extern "C" void kernel_launch(void* const* d_in, const int* in_sizes, int n_in,
                              void* d_out, int out_size, void* d_ws, size_t ws_size,
                              hipStream_t stream) {
    const float* x    = (const float*)d_in[0];
    const float* Wih  = (const float*)d_in[1];
    const float* Whh  = (const float*)d_in[2];
    const float* bih  = (const float*)d_in[3];
    const float* bhh  = (const float*)d_in[4];
    const float* Wout = (const float*)d_in[5];
    const float* bout = (const float*)d_in[6];
    float* out = (float*)d_out;

    float* hstate = (float*)d_ws;                       // 256*128*4 = 128 KiB
    void*  xg     = (void*)((char*)d_ws + 131072);
    const size_t avail = ws_size > 131072 ? ws_size - 131072 : 0;

    bool bf16;
    int CT;
    if (avail >= (size_t)BATCH * SEQ * NG * 4) {        // 201 MB fp32 xg
        bf16 = false; CT = SEQ;
    } else if (avail >= (size_t)BATCH * SEQ * NG * 2) { // 100 MB bf16 xg
        bf16 = true;  CT = SEQ;
    } else {                                            // chunked bf16
        bf16 = true;
        CT = 64;
        while (CT * 2 <= SEQ && avail >= (size_t)BATCH * (size_t)(CT * 2) * NG * 2) CT *= 2;
    }

    for (int t0 = 0; t0 < SEQ; t0 += CT) {
        dim3 gridA(NG / 64, (BATCH * CT) / 64);
        const int initial = (t0 == 0);
        const int final_chunk = (t0 + CT >= SEQ);
        if (bf16) {
            xg_gemm<true><<<gridA, 256, 0, stream>>>(x, Wih, bih, xg, t0, CT);
            gru_chunk<true><<<BATCH, 384, 0, stream>>>(xg, Whh, bhh, hstate, t0, CT,
                                                       initial, final_chunk, Wout, bout, out);
        } else {
            xg_gemm<false><<<gridA, 256, 0, stream>>>(x, Wih, bih, xg, t0, CT);
            gru_chunk<false><<<BATCH, 384, 0, stream>>>(xg, Whh, bhh, hstate, t0, CT,
                                                        initial, final_chunk, Wout, bout, out);
        }
    }
}

// Round 3
// 994.645 us; speedup vs baseline: 1.5975x; 1.5975x over previous
//
#include <hip/hip_runtime.h>
#include <hip/hip_bf16.h>
#include <math.h>

#define BATCH 256
#define SEQ   512
#define INS   300
#define KP    320   // K padded to 10 x 32
#define HID   128
#define NG    384   // 3*HID

typedef __attribute__((ext_vector_type(8))) short short8;   // 8 x bf16 (4 VGPRs)
typedef __attribute__((ext_vector_type(4))) float f32x4;

// ---------- helpers ----------
__device__ __forceinline__ float bf2f(unsigned short u) {
    unsigned int v = ((unsigned int)u) << 16;
    return __uint_as_float(v);
}
__device__ __forceinline__ unsigned short f2bf(float f) {
    unsigned int u = __float_as_uint(f);
    unsigned int r = (u + 0x7FFFu + ((u >> 16) & 1u)) >> 16;
    return (unsigned short)r;
}

// ---------- Kernel 0: split W_ih (fp32 384x300) -> bf16 hi/lo planes (384x320, k-padded) ----------
__global__ void conv_wih(const float* __restrict__ Wih,
                         unsigned short* __restrict__ Whi,
                         unsigned short* __restrict__ Wlo)
{
    int idx = blockIdx.x * 256 + threadIdx.x;     // 0 .. 384*320-1
    if (idx >= NG * KP) return;
    int g = idx / KP, k = idx - g * KP;
    float v = (k < INS) ? Wih[g * INS + k] : 0.f;
    unsigned short h = f2bf(v);
    float r = v - bf2f(h);
    Whi[idx] = h;
    Wlo[idx] = f2bf(r);
}

// ---------- Kernel A: xg = x @ W_ih^T + b_ih via split-bf16 MFMA ----------
// Tile: BM=128 rows x BN=128 gates, BK=32, 256 threads (4 waves), wave tile 64x64.
// grid.x = 3 (gate tiles), grid.y = rows/128.
template <bool BF16OUT>
__launch_bounds__(256)
__global__ void xg_mfma(const float* __restrict__ x,
                        const unsigned short* __restrict__ Whi,
                        const unsigned short* __restrict__ Wlo,
                        const float* __restrict__ bih,
                        void* __restrict__ xg_out,
                        int t0, int CT)
{
    __shared__ unsigned short Ah[128][40], Al[128][40];  // rows padded to 40 bf16 (80B)
    __shared__ unsigned short Bh[128][40], Bl[128][40];

    const int tid  = threadIdx.x;
    const int lane = tid & 63;
    const int w    = tid >> 6;          // wave 0..3
    const int wm   = (w & 1) * 64;
    const int wn   = (w >> 1) * 64;
    const int n0   = blockIdx.x * 128;  // gate tile origin
    const int m0   = blockIdx.y * 128;  // row tile origin

    // staging map: thread t -> row = t>>1 (0..127), half = t&1 (16 k-elems each)
    const int srow = tid >> 1;
    const int shalf = tid & 1;
    const int rr = m0 + srow;
    const int bb = rr / CT;
    const float* xrow = x + (size_t)(bb * SEQ + t0 + (rr - bb * CT)) * INS;

    f32x4 acc[4][4] = {};

    for (int ks = 0; ks < KP / 32; ks++) {
        const int k0 = ks * 32 + shalf * 16;
        // ---- stage A: load 16 fp32, split into bf16 hi/lo ----
        float v[16];
        #pragma unroll
        for (int i = 0; i < 16; i += 4) {
            if (k0 + i + 4 <= INS) {
                float4 f = *(const float4*)(xrow + k0 + i);
                v[i] = f.x; v[i + 1] = f.y; v[i + 2] = f.z; v[i + 3] = f.w;
            } else {
                #pragma unroll
                for (int j = 0; j < 4; j++)
                    v[i + j] = (k0 + i + j < INS) ? xrow[k0 + i + j] : 0.f;
            }
        }
        union { unsigned short us[8]; uint4 q; } ph, pl;
        #pragma unroll
        for (int gblk = 0; gblk < 2; gblk++) {
            #pragma unroll
            for (int i = 0; i < 8; i++) {
                float f = v[gblk * 8 + i];
                unsigned short h = f2bf(f);
                ph.us[i] = h;
                pl.us[i] = f2bf(f - bf2f(h));
            }
            *(uint4*)&Ah[srow][shalf * 16 + gblk * 8] = ph.q;
            *(uint4*)&Al[srow][shalf * 16 + gblk * 8] = pl.q;
        }
        // ---- stage B: copy pre-split bf16 planes ----
        {
            const size_t off = (size_t)(n0 + srow) * KP + ks * 32 + shalf * 16;
            const uint4* sh = (const uint4*)(Whi + off);
            const uint4* sl = (const uint4*)(Wlo + off);
            *(uint4*)&Bh[srow][shalf * 16]     = sh[0];
            *(uint4*)&Bh[srow][shalf * 16 + 8] = sh[1];
            *(uint4*)&Bl[srow][shalf * 16]     = sl[0];
            *(uint4*)&Bl[srow][shalf * 16 + 8] = sl[1];
        }
        __syncthreads();

        // ---- fragments + MFMA ----
        const int lm = lane & 15;
        const int lk = (lane >> 4) * 8;
        short8 ah[4], al[4], bh[4], bl[4];
        #pragma unroll
        for (int mi = 0; mi < 4; mi++) {
            ah[mi] = *(const short8*)&Ah[wm + mi * 16 + lm][lk];
            al[mi] = *(const short8*)&Al[wm + mi * 16 + lm][lk];
        }
        #pragma unroll
        for (int ni = 0; ni < 4; ni++) {
            bh[ni] = *(const short8*)&Bh[wn + ni * 16 + lm][lk];
            bl[ni] = *(const short8*)&Bl[wn + ni * 16 + lm][lk];
        }
        #pragma unroll
        for (int mi = 0; mi < 4; mi++) {
            #pragma unroll
            for (int ni = 0; ni < 4; ni++) {
                acc[mi][ni] = __builtin_amdgcn_mfma_f32_16x16x32_bf16(ah[mi], bh[ni], acc[mi][ni], 0, 0, 0);
                acc[mi][ni] = __builtin_amdgcn_mfma_f32_16x16x32_bf16(ah[mi], bl[ni], acc[mi][ni], 0, 0, 0);
                acc[mi][ni] = __builtin_amdgcn_mfma_f32_16x16x32_bf16(al[mi], bh[ni], acc[mi][ni], 0, 0, 0);
            }
        }
        __syncthreads();
    }

    // ---- epilogue: C/D layout col=lane&15, row=(lane>>4)*4+reg (m89-verified) ----
    const int crow = wm + ((lane >> 4) * 4);
    const int ccol = wn + (lane & 15);
    #pragma unroll
    for (int ni = 0; ni < 4; ni++) {
        const int col = n0 + ccol + ni * 16;
        const float bias = bih[col];
        #pragma unroll
        for (int mi = 0; mi < 4; mi++) {
            #pragma unroll
            for (int i = 0; i < 4; i++) {
                const size_t row = (size_t)(m0 + crow + mi * 16 + i);
                const float val = acc[mi][ni][i] + bias;
                if (BF16OUT) ((unsigned short*)xg_out)[row * NG + col] = f2bf(val);
                else         ((float*)xg_out)[row * NG + col] = val;
            }
        }
    }
}

// ---------- Kernel B: sequential GRU over a chunk of timesteps (unchanged from R1) ----------
template <bool BF16>
__launch_bounds__(384)
__global__ void gru_chunk(const void* __restrict__ xg_in,
                          const float* __restrict__ Whh,
                          const float* __restrict__ bhh,
                          float* __restrict__ hstate,
                          int t0, int CT, int initial, int final_chunk,
                          const float* __restrict__ Wout,
                          const float* __restrict__ bout,
                          float* __restrict__ out)
{
    const int b = blockIdx.x;
    const int g = threadIdx.x;   // 0..383

    __shared__ alignas(16) float h_s[HID];
    __shared__ alignas(16) float hg_s[NG];
    __shared__ alignas(16) float red[2][HID];

    float w[HID];
    const float* wr = Whh + (size_t)g * HID;
    #pragma unroll
    for (int k = 0; k < HID; k += 4) {
        float4 v = *(const float4*)&wr[k];
        w[k] = v.x; w[k + 1] = v.y; w[k + 2] = v.z; w[k + 3] = v.w;
    }
    const float bh = bhh[g];

    if (g < HID) h_s[g] = initial ? 0.f : hstate[b * HID + g];
    __syncthreads();

    const float* xgf = (const float*)xg_in;
    const unsigned short* xgb = (const unsigned short*)xg_in;

    for (int tt = 0; tt < CT; tt++) {
        const size_t base = ((size_t)b * CT + tt) * NG;
        float xr = 0.f, xz = 0.f, xn = 0.f;
        if (g < HID) {
            if (BF16) {
                xr = bf2f(xgb[base + g]);
                xz = bf2f(xgb[base + HID + g]);
                xn = bf2f(xgb[base + 2 * HID + g]);
            } else {
                xr = xgf[base + g];
                xz = xgf[base + HID + g];
                xn = xgf[base + 2 * HID + g];
            }
        }

        float a0 = 0.f, a1 = 0.f, a2 = 0.f, a3 = 0.f;
        #pragma unroll
        for (int k = 0; k < HID; k += 4) {
            float4 hv = *(const float4*)&h_s[k];
            a0 += hv.x * w[k];
            a1 += hv.y * w[k + 1];
            a2 += hv.z * w[k + 2];
            a3 += hv.w * w[k + 3];
        }
        hg_s[g] = bh + ((a0 + a1) + (a2 + a3));
        __syncthreads();

        if (g < HID) {
            float rg = 1.f / (1.f + __expf(-(xr + hg_s[g])));
            float zg = 1.f / (1.f + __expf(-(xz + hg_s[HID + g])));
            float nv = xn + rg * hg_s[2 * HID + g];
            float e  = __expf(2.f * nv);
            float ng = 1.f - 2.f / (e + 1.f);
            float hold = h_s[g];
            h_s[g] = (1.f - zg) * ng + zg * hold;
        }
        __syncthreads();
    }

    if (g < HID) hstate[b * HID + g] = h_s[g];

    if (final_chunk) {
        if (g < HID) {
            float f = h_s[g] > 0.f ? h_s[g] : 0.f;
            red[0][g] = f * Wout[g];
            red[1][g] = f * Wout[HID + g];
        }
        __syncthreads();
        if (g == 0) {
            float l0 = bout[0], l1 = bout[1];
            for (int k = 0; k < HID; k++) { l0 += red[0][k]; l1 += red[1][k]; }
            float m = fmaxf(l0, l1);
            float lse = m + logf(__expf(l0 - m) + __expf(l1 - m));
            out[b * 2 + 0] = l0 - lse;
            out[b * 2 + 1] = l1 - lse;
        }
    }
}

// ---------- launch ----------
extern "C" void kernel_launch(void* const* d_in, const int* in_sizes, int n_in,
                              void* d_out, int out_size, void* d_ws, size_t ws_size,
                              hipStream_t stream) {
    const float* x    = (const float*)d_in[0];
    const float* Wih  = (const float*)d_in[1];
    const float* Whh  = (const float*)d_in[2];
    const float* bih  = (const float*)d_in[3];
    const float* bhh  = (const float*)d_in[4];
    const float* Wout = (const float*)d_in[5];
    const float* bout = (const float*)d_in[6];
    float* out = (float*)d_out;

    // ws layout: [W_hi | W_lo | hstate | xg]
    unsigned short* Whi = (unsigned short*)d_ws;                       // 384*320*2 = 245760 B
    unsigned short* Wlo = (unsigned short*)((char*)d_ws + 245760);
    float* hstate = (float*)((char*)d_ws + 491520);                    // 128 KiB
    void*  xg     = (void*)((char*)d_ws + 622592);
    const size_t avail = ws_size > 622592 ? ws_size - 622592 : 0;

    bool bf16;
    int CT;
    if (avail >= (size_t)BATCH * SEQ * NG * 4) {        // fp32 xg (201 MB)
        bf16 = false; CT = SEQ;
    } else if (avail >= (size_t)BATCH * SEQ * NG * 2) { // bf16 xg (100 MB)
        bf16 = true;  CT = SEQ;
    } else {                                            // chunked bf16
        bf16 = true;
        CT = 64;
        while (CT * 2 <= SEQ && avail >= (size_t)BATCH * (size_t)(CT * 2) * NG * 2) CT *= 2;
    }

    conv_wih<<<(NG * KP + 255) / 256, 256, 0, stream>>>(Wih, Whi, Wlo);

    for (int t0 = 0; t0 < SEQ; t0 += CT) {
        dim3 gridA(NG / 128, (BATCH * CT) / 128);
        const int initial = (t0 == 0);
        const int final_chunk = (t0 + CT >= SEQ);
        if (bf16) {
            xg_mfma<true><<<gridA, 256, 0, stream>>>(x, Whi, Wlo, bih, xg, t0, CT);
            gru_chunk<true><<<BATCH, 384, 0, stream>>>(xg, Whh, bhh, hstate, t0, CT,
                                                       initial, final_chunk, Wout, bout, out);
        } else {
            xg_mfma<false><<<gridA, 256, 0, stream>>>(x, Whi, Wlo, bih, xg, t0, CT);
            gru_chunk<false><<<BATCH, 384, 0, stream>>>(xg, Whh, bhh, hstate, t0, CT,
                                                        initial, final_chunk, Wout, bout, out);
        }
    }
}

// Round 4
// 860.556 us; speedup vs baseline: 1.8464x; 1.1558x over previous
//
#include <hip/hip_runtime.h>
#include <hip/hip_bf16.h>
#include <math.h>

#define BATCH 256
#define SEQ   512
#define INS   300
#define KP    320   // K padded to 10 x 32 (xg gemm)
#define HID   128
#define NG    384   // 3*HID

typedef __attribute__((ext_vector_type(8))) short short8;   // 8 x bf16 (4 VGPRs)
typedef __attribute__((ext_vector_type(4))) float f32x4;

// ---------- helpers ----------
__device__ __forceinline__ float bf2f(unsigned short u) {
    unsigned int v = ((unsigned int)u) << 16;
    return __uint_as_float(v);
}
__device__ __forceinline__ unsigned short f2bf(float f) {
    unsigned int u = __float_as_uint(f);
    unsigned int r = (u + 0x7FFFu + ((u >> 16) & 1u)) >> 16;
    return (unsigned short)r;
}

// ---------- Kernel 0: split W_ih (fp32 384x300) -> bf16 hi/lo planes (384x320, k-padded) ----------
__global__ void conv_wih(const float* __restrict__ Wih,
                         unsigned short* __restrict__ Whi,
                         unsigned short* __restrict__ Wlo)
{
    int idx = blockIdx.x * 256 + threadIdx.x;     // 0 .. 384*320-1
    if (idx >= NG * KP) return;
    int g = idx / KP, k = idx - g * KP;
    float v = (k < INS) ? Wih[g * INS + k] : 0.f;
    unsigned short h = f2bf(v);
    float r = v - bf2f(h);
    Whi[idx] = h;
    Wlo[idx] = f2bf(r);
}

// ---------- Kernel A: xg = x @ W_ih^T + b_ih via split-bf16 MFMA (unchanged from R3) ----------
template <bool BF16OUT>
__launch_bounds__(256)
__global__ void xg_mfma(const float* __restrict__ x,
                        const unsigned short* __restrict__ Whi,
                        const unsigned short* __restrict__ Wlo,
                        const float* __restrict__ bih,
                        void* __restrict__ xg_out,
                        int t0, int CT)
{
    __shared__ unsigned short Ah[128][40], Al[128][40];
    __shared__ unsigned short Bh[128][40], Bl[128][40];

    const int tid  = threadIdx.x;
    const int lane = tid & 63;
    const int w    = tid >> 6;
    const int wm   = (w & 1) * 64;
    const int wn   = (w >> 1) * 64;
    const int n0   = blockIdx.x * 128;
    const int m0   = blockIdx.y * 128;

    const int srow = tid >> 1;
    const int shalf = tid & 1;
    const int rr = m0 + srow;
    const int bb = rr / CT;
    const float* xrow = x + (size_t)(bb * SEQ + t0 + (rr - bb * CT)) * INS;

    f32x4 acc[4][4] = {};

    for (int ks = 0; ks < KP / 32; ks++) {
        const int k0 = ks * 32 + shalf * 16;
        float v[16];
        #pragma unroll
        for (int i = 0; i < 16; i += 4) {
            if (k0 + i + 4 <= INS) {
                float4 f = *(const float4*)(xrow + k0 + i);
                v[i] = f.x; v[i + 1] = f.y; v[i + 2] = f.z; v[i + 3] = f.w;
            } else {
                #pragma unroll
                for (int j = 0; j < 4; j++)
                    v[i + j] = (k0 + i + j < INS) ? xrow[k0 + i + j] : 0.f;
            }
        }
        union { unsigned short us[8]; uint4 q; } ph, pl;
        #pragma unroll
        for (int gblk = 0; gblk < 2; gblk++) {
            #pragma unroll
            for (int i = 0; i < 8; i++) {
                float f = v[gblk * 8 + i];
                unsigned short h = f2bf(f);
                ph.us[i] = h;
                pl.us[i] = f2bf(f - bf2f(h));
            }
            *(uint4*)&Ah[srow][shalf * 16 + gblk * 8] = ph.q;
            *(uint4*)&Al[srow][shalf * 16 + gblk * 8] = pl.q;
        }
        {
            const size_t off = (size_t)(n0 + srow) * KP + ks * 32 + shalf * 16;
            const uint4* sh = (const uint4*)(Whi + off);
            const uint4* sl = (const uint4*)(Wlo + off);
            *(uint4*)&Bh[srow][shalf * 16]     = sh[0];
            *(uint4*)&Bh[srow][shalf * 16 + 8] = sh[1];
            *(uint4*)&Bl[srow][shalf * 16]     = sl[0];
            *(uint4*)&Bl[srow][shalf * 16 + 8] = sl[1];
        }
        __syncthreads();

        const int lm = lane & 15;
        const int lk = (lane >> 4) * 8;
        short8 ah[4], al[4], bh[4], bl[4];
        #pragma unroll
        for (int mi = 0; mi < 4; mi++) {
            ah[mi] = *(const short8*)&Ah[wm + mi * 16 + lm][lk];
            al[mi] = *(const short8*)&Al[wm + mi * 16 + lm][lk];
        }
        #pragma unroll
        for (int ni = 0; ni < 4; ni++) {
            bh[ni] = *(const short8*)&Bh[wn + ni * 16 + lm][lk];
            bl[ni] = *(const short8*)&Bl[wn + ni * 16 + lm][lk];
        }
        #pragma unroll
        for (int mi = 0; mi < 4; mi++) {
            #pragma unroll
            for (int ni = 0; ni < 4; ni++) {
                acc[mi][ni] = __builtin_amdgcn_mfma_f32_16x16x32_bf16(ah[mi], bh[ni], acc[mi][ni], 0, 0, 0);
                acc[mi][ni] = __builtin_amdgcn_mfma_f32_16x16x32_bf16(ah[mi], bl[ni], acc[mi][ni], 0, 0, 0);
                acc[mi][ni] = __builtin_amdgcn_mfma_f32_16x16x32_bf16(al[mi], bh[ni], acc[mi][ni], 0, 0, 0);
            }
        }
        __syncthreads();
    }

    const int crow = wm + ((lane >> 4) * 4);
    const int ccol = wn + (lane & 15);
    #pragma unroll
    for (int ni = 0; ni < 4; ni++) {
        const int col = n0 + ccol + ni * 16;
        const float bias = bih[col];
        #pragma unroll
        for (int mi = 0; mi < 4; mi++) {
            #pragma unroll
            for (int i = 0; i < 4; i++) {
                const size_t row = (size_t)(m0 + crow + mi * 16 + i);
                const float val = acc[mi][ni][i] + bias;
                if (BF16OUT) ((unsigned short*)xg_out)[row * NG + col] = f2bf(val);
                else         ((float*)xg_out)[row * NG + col] = val;
            }
        }
    }
}

// ---------- Kernel B: MFMA recurrence ----------
// 1 block per batch row, 256 threads (4 waves). W_hh held in VGPRs as split-bf16
// A-fragments for the whole kernel. Per step: hg = W·h via 72 MFMAs/wave
// (N-dim broadcast-wasted), h broadcast from LDS (8 ds_read_b128/lane vs 32
// before), activation on lanes 0-31 of each wave (wave w owns hidden slice
// [32w,32w+32) across all three gates -> hg never crosses waves -> single
// raw s_barrier per step; h double-buffered so no second barrier).
template <bool BF16XG>
__launch_bounds__(256, 1)
__global__ void gru_mfma(const void* __restrict__ xg_in,
                         const float* __restrict__ Whh,
                         const float* __restrict__ bhh,
                         float* __restrict__ hstate,
                         int t0, int CT, int initial, int final_chunk,
                         const float* __restrict__ Wout,
                         const float* __restrict__ bout,
                         float* __restrict__ out)
{
    const int b    = blockIdx.x;
    const int tid  = threadIdx.x;
    const int w    = tid >> 6;
    const int lane = tid & 63;
    const int lm   = lane & 15;
    const int quad = lane >> 4;

    __shared__ alignas(16) unsigned short h_hi[2][HID];
    __shared__ alignas(16) unsigned short h_lo[2][HID];
    __shared__ alignas(16) float hg_s[NG];
    __shared__ alignas(16) float red[2 * HID];

    // wave w's M-tiles: r-gates [32w,32w+32), z-gates, n-gates
    const int mt0 = 2 * w, mt2 = 8 + 2 * w, mt4 = 16 + 2 * w;
    const int mts[6] = {mt0, mt0 + 1, mt2, mt2 + 1, mt4, mt4 + 1};

    // ---- load W_hh A-fragments, split bf16 hi/lo (stays in VGPRs all steps) ----
    short8 a_hi[6][4], a_lo[6][4];
    #pragma unroll
    for (int t = 0; t < 6; t++) {
        const float* wrow = Whh + (size_t)(mts[t] * 16 + lm) * HID + quad * 8;
        #pragma unroll
        for (int kt = 0; kt < 4; kt++) {
            float4 f0 = *(const float4*)(wrow + kt * 32);
            float4 f1 = *(const float4*)(wrow + kt * 32 + 4);
            float vv[8] = {f0.x, f0.y, f0.z, f0.w, f1.x, f1.y, f1.z, f1.w};
            short8 h8, l8;
            #pragma unroll
            for (int i = 0; i < 8; i++) {
                unsigned short h = f2bf(vv[i]);
                h8[i] = (short)h;
                l8[i] = (short)f2bf(vv[i] - bf2f(h));
            }
            a_hi[t][kt] = h8;
            a_lo[t][kt] = l8;
        }
    }

    // ---- per-activation-lane state (lanes 0-31 of each wave own j = 32w+lane) ----
    const int j = w * 32 + lane;   // valid only when lane < 32
    float hprev = 0.f, bhr = 0.f, bhz = 0.f, bhn = 0.f, wo0 = 0.f, wo1 = 0.f;
    float nxr = 0.f, nxz = 0.f, nxn = 0.f;
    const float* xgf = (const float*)xg_in;
    const unsigned short* xgb = (const unsigned short*)xg_in;

    if (lane < 32) {
        hprev = initial ? 0.f : hstate[b * HID + j];
        bhr = bhh[j]; bhz = bhh[HID + j]; bhn = bhh[2 * HID + j];
        wo0 = Wout[j]; wo1 = Wout[HID + j];
        unsigned short hh = f2bf(hprev);
        h_hi[0][j] = hh;
        h_lo[0][j] = f2bf(hprev - bf2f(hh));
        // prefetch xg for step 0
        const size_t nb = (size_t)b * CT * NG;
        if (BF16XG) { nxr = bf2f(xgb[nb + j]); nxz = bf2f(xgb[nb + HID + j]); nxn = bf2f(xgb[nb + 2 * HID + j]); }
        else        { nxr = xgf[nb + j];       nxz = xgf[nb + HID + j];       nxn = xgf[nb + 2 * HID + j]; }
    }
    __syncthreads();

    for (int tt = 0; tt < CT; tt++) {
        const int p = tt & 1;
        // ---- B fragments: h broadcast (all 16 N-columns identical) ----
        short8 bhfr[4], blfr[4];
        #pragma unroll
        for (int kt = 0; kt < 4; kt++) {
            bhfr[kt] = *(const short8*)&h_hi[p][kt * 32 + quad * 8];
            blfr[kt] = *(const short8*)&h_lo[p][kt * 32 + quad * 8];
        }
        // ---- hg = (Whi+Wlo)(hhi+hlo) minus lo*lo: 72 MFMAs, 6 indep acc chains ----
        f32x4 acc[6] = {};
        #pragma unroll
        for (int kt = 0; kt < 4; kt++) {
            #pragma unroll
            for (int t = 0; t < 6; t++)
                acc[t] = __builtin_amdgcn_mfma_f32_16x16x32_bf16(a_hi[t][kt], bhfr[kt], acc[t], 0, 0, 0);
            #pragma unroll
            for (int t = 0; t < 6; t++)
                acc[t] = __builtin_amdgcn_mfma_f32_16x16x32_bf16(a_lo[t][kt], bhfr[kt], acc[t], 0, 0, 0);
            #pragma unroll
            for (int t = 0; t < 6; t++)
                acc[t] = __builtin_amdgcn_mfma_f32_16x16x32_bf16(a_hi[t][kt], blfr[kt], acc[t], 0, 0, 0);
        }
        // ---- spill hg to LDS (col-0 lanes; each wave writes only its own tiles) ----
        if (lm == 0) {
            #pragma unroll
            for (int t = 0; t < 6; t++)
                *(f32x4*)&hg_s[mts[t] * 16 + quad * 4] = acc[t];
        }
        asm volatile("s_waitcnt lgkmcnt(0)" ::: "memory");   // wave-local: hg writes visible to own wave's reads

        // ---- activation (lanes 0-31 of each wave) ----
        if (lane < 32) {
            float xr = nxr, xz = nxz, xn = nxn;
            float hgr = hg_s[j] + bhr;
            float hgz = hg_s[HID + j] + bhz;
            float hgn = hg_s[2 * HID + j] + bhn;
            float rg = 1.f / (1.f + __expf(-(xr + hgr)));
            float zg = 1.f / (1.f + __expf(-(xz + hgz)));
            float nv = xn + rg * hgn;
            float e  = __expf(2.f * nv);
            float ng = 1.f - 2.f / (e + 1.f);
            hprev = (1.f - zg) * ng + zg * hprev;
            unsigned short hh = f2bf(hprev);
            h_hi[1 - p][j] = hh;
            h_lo[1 - p][j] = f2bf(hprev - bf2f(hh));
            if (tt + 1 < CT) {   // prefetch next step's xg (stays in flight across barrier)
                const size_t nb = ((size_t)b * CT + tt + 1) * NG;
                if (BF16XG) { nxr = bf2f(xgb[nb + j]); nxz = bf2f(xgb[nb + HID + j]); nxn = bf2f(xgb[nb + 2 * HID + j]); }
                else        { nxr = xgf[nb + j];       nxz = xgf[nb + HID + j];       nxn = xgf[nb + 2 * HID + j]; }
            }
        }
        // raw barrier: drain LDS only; do NOT drain vmcnt (keeps prefetch async)
        asm volatile("s_waitcnt lgkmcnt(0)\ns_barrier" ::: "memory");
    }

    if (lane < 32) hstate[b * HID + j] = hprev;

    // ---- head: relu -> 2-class linear -> log_softmax ----
    if (final_chunk) {
        if (lane < 32) {
            float f = hprev > 0.f ? hprev : 0.f;
            red[j] = f * wo0;
            red[HID + j] = f * wo1;
        }
        __syncthreads();
        if (tid < 64) {
            float l0 = red[tid] + red[64 + tid];
            float l1 = red[HID + tid] + red[HID + 64 + tid];
            #pragma unroll
            for (int d = 32; d > 0; d >>= 1) {
                l0 += __shfl_down(l0, d, 64);
                l1 += __shfl_down(l1, d, 64);
            }
            if (tid == 0) {
                l0 += bout[0]; l1 += bout[1];
                float m = fmaxf(l0, l1);
                float lse = m + logf(__expf(l0 - m) + __expf(l1 - m));
                out[b * 2 + 0] = l0 - lse;
                out[b * 2 + 1] = l1 - lse;
            }
        }
    }
}

// ---------- launch ----------
extern "C" void kernel_launch(void* const* d_in, const int* in_sizes, int n_in,
                              void* d_out, int out_size, void* d_ws, size_t ws_size,
                              hipStream_t stream) {
    const float* x    = (const float*)d_in[0];
    const float* Wih  = (const float*)d_in[1];
    const float* Whh  = (const float*)d_in[2];
    const float* bih  = (const float*)d_in[3];
    const float* bhh  = (const float*)d_in[4];
    const float* Wout = (const float*)d_in[5];
    const float* bout = (const float*)d_in[6];
    float* out = (float*)d_out;

    // ws layout: [W_hi | W_lo | hstate | xg]
    unsigned short* Whi = (unsigned short*)d_ws;                       // 384*320*2 = 245760 B
    unsigned short* Wlo = (unsigned short*)((char*)d_ws + 245760);
    float* hstate = (float*)((char*)d_ws + 491520);                    // 128 KiB
    void*  xg     = (void*)((char*)d_ws + 622592);
    const size_t avail = ws_size > 622592 ? ws_size - 622592 : 0;

    bool bf16;
    int CT;
    if (avail >= (size_t)BATCH * SEQ * NG * 4) {        // fp32 xg (201 MB)
        bf16 = false; CT = SEQ;
    } else if (avail >= (size_t)BATCH * SEQ * NG * 2) { // bf16 xg (100 MB)
        bf16 = true;  CT = SEQ;
    } else {                                            // chunked bf16
        bf16 = true;
        CT = 64;
        while (CT * 2 <= SEQ && avail >= (size_t)BATCH * (size_t)(CT * 2) * NG * 2) CT *= 2;
    }

    conv_wih<<<(NG * KP + 255) / 256, 256, 0, stream>>>(Wih, Whi, Wlo);

    for (int t0 = 0; t0 < SEQ; t0 += CT) {
        dim3 gridA(NG / 128, (BATCH * CT) / 128);
        const int initial = (t0 == 0);
        const int final_chunk = (t0 + CT >= SEQ);
        if (bf16) {
            xg_mfma<true><<<gridA, 256, 0, stream>>>(x, Whi, Wlo, bih, xg, t0, CT);
            gru_mfma<true><<<BATCH, 256, 0, stream>>>(xg, Whh, bhh, hstate, t0, CT,
                                                      initial, final_chunk, Wout, bout, out);
        } else {
            xg_mfma<false><<<gridA, 256, 0, stream>>>(x, Whi, Wlo, bih, xg, t0, CT);
            gru_mfma<false><<<BATCH, 256, 0, stream>>>(xg, Whh, bhh, hstate, t0, CT,
                                                       initial, final_chunk, Wout, bout, out);
        }
    }
}

// Round 5
// 832.468 us; speedup vs baseline: 1.9087x; 1.0337x over previous
//
#include <hip/hip_runtime.h>
#include <hip/hip_bf16.h>
#include <math.h>

#define BATCH 256
#define SEQ   512
#define INS   300
#define KP    320   // K padded to 10 x 32 (xg gemm)
#define HID   128
#define NG    384   // 3*HID

typedef __attribute__((ext_vector_type(8))) short short8;   // 8 x bf16 (4 VGPRs)
typedef __attribute__((ext_vector_type(4))) float f32x4;

// ---------- helpers ----------
__device__ __forceinline__ float bf2f(unsigned short u) {
    unsigned int v = ((unsigned int)u) << 16;
    return __uint_as_float(v);
}
__device__ __forceinline__ unsigned short f2bf(float f) {
    unsigned int u = __float_as_uint(f);
    unsigned int r = (u + 0x7FFFu + ((u >> 16) & 1u)) >> 16;
    return (unsigned short)r;
}

// ---------- Kernel 0: split W_ih (fp32 384x300) -> bf16 hi/lo planes (384x320, k-padded) ----------
__global__ void conv_wih(const float* __restrict__ Wih,
                         unsigned short* __restrict__ Whi,
                         unsigned short* __restrict__ Wlo)
{
    int idx = blockIdx.x * 256 + threadIdx.x;     // 0 .. 384*320-1
    if (idx >= NG * KP) return;
    int g = idx / KP, k = idx - g * KP;
    float v = (k < INS) ? Wih[g * INS + k] : 0.f;
    unsigned short h = f2bf(v);
    float r = v - bf2f(h);
    Whi[idx] = h;
    Wlo[idx] = f2bf(r);
}

// ---------- Kernel A: xg = x @ W_ih^T + b_ih via split-bf16 MFMA (unchanged) ----------
template <bool BF16OUT>
__launch_bounds__(256)
__global__ void xg_mfma(const float* __restrict__ x,
                        const unsigned short* __restrict__ Whi,
                        const unsigned short* __restrict__ Wlo,
                        const float* __restrict__ bih,
                        void* __restrict__ xg_out,
                        int t0, int CT)
{
    __shared__ unsigned short Ah[128][40], Al[128][40];
    __shared__ unsigned short Bh[128][40], Bl[128][40];

    const int tid  = threadIdx.x;
    const int lane = tid & 63;
    const int w    = tid >> 6;
    const int wm   = (w & 1) * 64;
    const int wn   = (w >> 1) * 64;
    const int n0   = blockIdx.x * 128;
    const int m0   = blockIdx.y * 128;

    const int srow = tid >> 1;
    const int shalf = tid & 1;
    const int rr = m0 + srow;
    const int bb = rr / CT;
    const float* xrow = x + (size_t)(bb * SEQ + t0 + (rr - bb * CT)) * INS;

    f32x4 acc[4][4] = {};

    for (int ks = 0; ks < KP / 32; ks++) {
        const int k0 = ks * 32 + shalf * 16;
        float v[16];
        #pragma unroll
        for (int i = 0; i < 16; i += 4) {
            if (k0 + i + 4 <= INS) {
                float4 f = *(const float4*)(xrow + k0 + i);
                v[i] = f.x; v[i + 1] = f.y; v[i + 2] = f.z; v[i + 3] = f.w;
            } else {
                #pragma unroll
                for (int j = 0; j < 4; j++)
                    v[i + j] = (k0 + i + j < INS) ? xrow[k0 + i + j] : 0.f;
            }
        }
        union { unsigned short us[8]; uint4 q; } ph, pl;
        #pragma unroll
        for (int gblk = 0; gblk < 2; gblk++) {
            #pragma unroll
            for (int i = 0; i < 8; i++) {
                float f = v[gblk * 8 + i];
                unsigned short h = f2bf(f);
                ph.us[i] = h;
                pl.us[i] = f2bf(f - bf2f(h));
            }
            *(uint4*)&Ah[srow][shalf * 16 + gblk * 8] = ph.q;
            *(uint4*)&Al[srow][shalf * 16 + gblk * 8] = pl.q;
        }
        {
            const size_t off = (size_t)(n0 + srow) * KP + ks * 32 + shalf * 16;
            const uint4* sh = (const uint4*)(Whi + off);
            const uint4* sl = (const uint4*)(Wlo + off);
            *(uint4*)&Bh[srow][shalf * 16]     = sh[0];
            *(uint4*)&Bh[srow][shalf * 16 + 8] = sh[1];
            *(uint4*)&Bl[srow][shalf * 16]     = sl[0];
            *(uint4*)&Bl[srow][shalf * 16 + 8] = sl[1];
        }
        __syncthreads();

        const int lm = lane & 15;
        const int lk = (lane >> 4) * 8;
        short8 ah[4], al[4], bh[4], bl[4];
        #pragma unroll
        for (int mi = 0; mi < 4; mi++) {
            ah[mi] = *(const short8*)&Ah[wm + mi * 16 + lm][lk];
            al[mi] = *(const short8*)&Al[wm + mi * 16 + lm][lk];
        }
        #pragma unroll
        for (int ni = 0; ni < 4; ni++) {
            bh[ni] = *(const short8*)&Bh[wn + ni * 16 + lm][lk];
            bl[ni] = *(const short8*)&Bl[wn + ni * 16 + lm][lk];
        }
        #pragma unroll
        for (int mi = 0; mi < 4; mi++) {
            #pragma unroll
            for (int ni = 0; ni < 4; ni++) {
                acc[mi][ni] = __builtin_amdgcn_mfma_f32_16x16x32_bf16(ah[mi], bh[ni], acc[mi][ni], 0, 0, 0);
                acc[mi][ni] = __builtin_amdgcn_mfma_f32_16x16x32_bf16(ah[mi], bl[ni], acc[mi][ni], 0, 0, 0);
                acc[mi][ni] = __builtin_amdgcn_mfma_f32_16x16x32_bf16(al[mi], bh[ni], acc[mi][ni], 0, 0, 0);
            }
        }
        __syncthreads();
    }

    const int crow = wm + ((lane >> 4) * 4);
    const int ccol = wn + (lane & 15);
    #pragma unroll
    for (int ni = 0; ni < 4; ni++) {
        const int col = n0 + ccol + ni * 16;
        const float bias = bih[col];
        #pragma unroll
        for (int mi = 0; mi < 4; mi++) {
            #pragma unroll
            for (int i = 0; i < 4; i++) {
                const size_t row = (size_t)(m0 + crow + mi * 16 + i);
                const float val = acc[mi][ni][i] + bias;
                if (BF16OUT) ((unsigned short*)xg_out)[row * NG + col] = f2bf(val);
                else         ((float*)xg_out)[row * NG + col] = val;
            }
        }
    }
}

// ---------- Kernel B: MFMA recurrence, operand-swapped ----------
// A = broadcast h (per-step, from LDS), B = W_hh^T fragments (persistent in
// VGPRs). D col = lane&15 = gate index, D rows all identical -> each
// activation lane holds its gate values IN REGISTERS (1 cndmask per gate;
// no hg LDS round trip). 3 product paths in separate accumulators
// (18 indep depth-4 chains). One raw barrier per step; h double-buffered.
template <bool BF16XG>
__launch_bounds__(256, 1)
__global__ void gru_mfma(const void* __restrict__ xg_in,
                         const float* __restrict__ Whh,
                         const float* __restrict__ bhh,
                         float* __restrict__ hstate,
                         int t0, int CT, int initial, int final_chunk,
                         const float* __restrict__ Wout,
                         const float* __restrict__ bout,
                         float* __restrict__ out)
{
    const int b    = blockIdx.x;
    const int tid  = threadIdx.x;
    const int w    = tid >> 6;
    const int lane = tid & 63;
    const int lm   = lane & 15;
    const int quad = lane >> 4;

    __shared__ alignas(16) unsigned short h_hi[2][HID];
    __shared__ alignas(16) unsigned short h_lo[2][HID];
    __shared__ alignas(16) float red[2 * HID];

    // wave w's N-tiles (16 gate-cols each): r: {2w,2w+1}, z: {8+2w,...}, n: {16+2w,...}
    const int mt0 = 2 * w, mt2 = 8 + 2 * w, mt4 = 16 + 2 * w;
    const int mts[6] = {mt0, mt0 + 1, mt2, mt2 + 1, mt4, mt4 + 1};

    // ---- persistent B fragments: B[k=32kt+quad*8+j][n=tile*16+lm] = Whh[n][k] ----
    short8 w_hi[6][4], w_lo[6][4];
    #pragma unroll
    for (int t = 0; t < 6; t++) {
        const float* wrow = Whh + (size_t)(mts[t] * 16 + lm) * HID + quad * 8;
        #pragma unroll
        for (int kt = 0; kt < 4; kt++) {
            float4 f0 = *(const float4*)(wrow + kt * 32);
            float4 f1 = *(const float4*)(wrow + kt * 32 + 4);
            float vv[8] = {f0.x, f0.y, f0.z, f0.w, f1.x, f1.y, f1.z, f1.w};
            short8 h8, l8;
            #pragma unroll
            for (int i = 0; i < 8; i++) {
                unsigned short h = f2bf(vv[i]);
                h8[i] = (short)h;
                l8[i] = (short)f2bf(vv[i] - bf2f(h));
            }
            w_hi[t][kt] = h8;
            w_lo[t][kt] = l8;
        }
    }

    // ---- per-activation-lane state (lanes 0-31 of wave w own j = 32w+lane) ----
    const int j = w * 32 + lane;   // valid when lane < 32
    float hprev = 0.f, bhr = 0.f, bhz = 0.f, bhn = 0.f, wo0 = 0.f, wo1 = 0.f;
    float nxr = 0.f, nxz = 0.f, nxn = 0.f;
    const float* xgf = (const float*)xg_in;
    const unsigned short* xgb = (const unsigned short*)xg_in;

    if (lane < 32) {
        hprev = initial ? 0.f : hstate[b * HID + j];
        bhr = bhh[j]; bhz = bhh[HID + j]; bhn = bhh[2 * HID + j];
        wo0 = Wout[j]; wo1 = Wout[HID + j];
        unsigned short hh = f2bf(hprev);
        h_hi[0][j] = hh;
        h_lo[0][j] = f2bf(hprev - bf2f(hh));
        const size_t nb = (size_t)b * CT * NG;
        if (BF16XG) { nxr = bf2f(xgb[nb + j]); nxz = bf2f(xgb[nb + HID + j]); nxn = bf2f(xgb[nb + 2 * HID + j]); }
        else        { nxr = xgf[nb + j];       nxz = xgf[nb + HID + j];       nxn = xgf[nb + 2 * HID + j]; }
    }
    __syncthreads();

    for (int tt = 0; tt < CT; tt++) {
        const int p = tt & 1;
        // ---- A fragments: broadcast h, A[m][k=quad*8+j] = h[k] (lane-indep per quad) ----
        short8 ah[4], al[4];
        #pragma unroll
        for (int kt = 0; kt < 4; kt++) {
            ah[kt] = *(const short8*)&h_hi[p][kt * 32 + quad * 8];
            al[kt] = *(const short8*)&h_lo[p][kt * 32 + quad * 8];
        }
        // ---- 18 independent depth-4 MFMA chains ----
        f32x4 ahh[6] = {}, alh[6] = {}, ahl[6] = {};
        #pragma unroll
        for (int kt = 0; kt < 4; kt++) {
            #pragma unroll
            for (int t = 0; t < 6; t++)
                ahh[t] = __builtin_amdgcn_mfma_f32_16x16x32_bf16(ah[kt], w_hi[t][kt], ahh[t], 0, 0, 0);
            #pragma unroll
            for (int t = 0; t < 6; t++)
                alh[t] = __builtin_amdgcn_mfma_f32_16x16x32_bf16(al[kt], w_hi[t][kt], alh[t], 0, 0, 0);
            #pragma unroll
            for (int t = 0; t < 6; t++)
                ahl[t] = __builtin_amdgcn_mfma_f32_16x16x32_bf16(ah[kt], w_lo[t][kt], ahl[t], 0, 0, 0);
        }
        // ---- merge paths (rows identical -> reg 0 suffices) ----
        float m0 = ahh[0][0] + alh[0][0] + ahl[0][0];
        float m1 = ahh[1][0] + alh[1][0] + ahl[1][0];
        float m2 = ahh[2][0] + alh[2][0] + ahl[2][0];
        float m3 = ahh[3][0] + alh[3][0] + ahl[3][0];
        float m4 = ahh[4][0] + alh[4][0] + ahl[4][0];
        float m5 = ahh[5][0] + alh[5][0] + ahl[5][0];

        // ---- activation: lane (0..31) holds col lane&15 of tile (lane>>4) ----
        if (lane < 32) {
            const bool hi16 = (lane & 16) != 0;
            float hgr = (hi16 ? m1 : m0) + bhr;
            float hgz = (hi16 ? m3 : m2) + bhz;
            float hgn = (hi16 ? m5 : m4) + bhn;
            float rg = 1.f / (1.f + __expf(-(nxr + hgr)));
            float zg = 1.f / (1.f + __expf(-(nxz + hgz)));
            float nv = nxn + rg * hgn;
            float e  = __expf(2.f * nv);
            float ng = 1.f - 2.f / (e + 1.f);
            hprev = (1.f - zg) * ng + zg * hprev;
            unsigned short hh = f2bf(hprev);
            h_hi[1 - p][j] = hh;
            h_lo[1 - p][j] = f2bf(hprev - bf2f(hh));
            if (tt + 1 < CT) {   // prefetch next xg; stays in flight across barrier
                const size_t nb = ((size_t)b * CT + tt + 1) * NG;
                if (BF16XG) { nxr = bf2f(xgb[nb + j]); nxz = bf2f(xgb[nb + HID + j]); nxn = bf2f(xgb[nb + 2 * HID + j]); }
                else        { nxr = xgf[nb + j];       nxz = xgf[nb + HID + j];       nxn = xgf[nb + 2 * HID + j]; }
            }
        }
        // drain LDS writes only (not vmcnt), then barrier
        asm volatile("s_waitcnt lgkmcnt(0)\ns_barrier" ::: "memory");
    }

    if (lane < 32) hstate[b * HID + j] = hprev;

    // ---- head: relu -> 2-class linear -> log_softmax ----
    if (final_chunk) {
        if (lane < 32) {
            float f = hprev > 0.f ? hprev : 0.f;
            red[j] = f * wo0;
            red[HID + j] = f * wo1;
        }
        __syncthreads();
        if (tid < 64) {
            float l0 = red[tid] + red[64 + tid];
            float l1 = red[HID + tid] + red[HID + 64 + tid];
            #pragma unroll
            for (int d = 32; d > 0; d >>= 1) {
                l0 += __shfl_down(l0, d, 64);
                l1 += __shfl_down(l1, d, 64);
            }
            if (tid == 0) {
                l0 += bout[0]; l1 += bout[1];
                float m = fmaxf(l0, l1);
                float lse = m + logf(__expf(l0 - m) + __expf(l1 - m));
                out[b * 2 + 0] = l0 - lse;
                out[b * 2 + 1] = l1 - lse;
            }
        }
    }
}

// ---------- launch ----------
extern "C" void kernel_launch(void* const* d_in, const int* in_sizes, int n_in,
                              void* d_out, int out_size, void* d_ws, size_t ws_size,
                              hipStream_t stream) {
    const float* x    = (const float*)d_in[0];
    const float* Wih  = (const float*)d_in[1];
    const float* Whh  = (const float*)d_in[2];
    const float* bih  = (const float*)d_in[3];
    const float* bhh  = (const float*)d_in[4];
    const float* Wout = (const float*)d_in[5];
    const float* bout = (const float*)d_in[6];
    float* out = (float*)d_out;

    // ws layout: [W_hi | W_lo | hstate | xg]
    unsigned short* Whi = (unsigned short*)d_ws;                       // 384*320*2 = 245760 B
    unsigned short* Wlo = (unsigned short*)((char*)d_ws + 245760);
    float* hstate = (float*)((char*)d_ws + 491520);                    // 128 KiB
    void*  xg     = (void*)((char*)d_ws + 622592);
    const size_t avail = ws_size > 622592 ? ws_size - 622592 : 0;

    bool bf16;
    int CT;
    if (avail >= (size_t)BATCH * SEQ * NG * 4) {        // fp32 xg (201 MB)
        bf16 = false; CT = SEQ;
    } else if (avail >= (size_t)BATCH * SEQ * NG * 2) { // bf16 xg (100 MB)
        bf16 = true;  CT = SEQ;
    } else {                                            // chunked bf16
        bf16 = true;
        CT = 64;
        while (CT * 2 <= SEQ && avail >= (size_t)BATCH * (size_t)(CT * 2) * NG * 2) CT *= 2;
    }

    conv_wih<<<(NG * KP + 255) / 256, 256, 0, stream>>>(Wih, Whi, Wlo);

    for (int t0 = 0; t0 < SEQ; t0 += CT) {
        dim3 gridA(NG / 128, (BATCH * CT) / 128);
        const int initial = (t0 == 0);
        const int final_chunk = (t0 + CT >= SEQ);
        if (bf16) {
            xg_mfma<true><<<gridA, 256, 0, stream>>>(x, Whi, Wlo, bih, xg, t0, CT);
            gru_mfma<true><<<BATCH, 256, 0, stream>>>(xg, Whh, bhh, hstate, t0, CT,
                                                      initial, final_chunk, Wout, bout, out);
        } else {
            xg_mfma<false><<<gridA, 256, 0, stream>>>(x, Whi, Wlo, bih, xg, t0, CT);
            gru_mfma<false><<<BATCH, 256, 0, stream>>>(xg, Whh, bhh, hstate, t0, CT,
                                                       initial, final_chunk, Wout, bout, out);
        }
    }
}